// Round 6
// baseline (19514.136 us; speedup 1.0000x reference)
//
#include <hip/hip_runtime.h>
#include <math.h>

#define TT 19
#define TPREV 10

typedef __attribute__((ext_vector_type(8))) short bf8v;
typedef __attribute__((ext_vector_type(4))) float f4v;

__device__ __forceinline__ float sigmoidf_(float x){ return 1.f/(1.f+expf(-x)); }
__device__ __forceinline__ unsigned short f2bf(float x){
    unsigned int u = __float_as_uint(x);
    u += 0x7FFFu + ((u>>16)&1u);
    return (unsigned short)(u>>16);
}
__device__ __forceinline__ float bf2f(unsigned short b){ return __uint_as_float(((unsigned int)b)<<16); }

// RULE (R4, keep forever): NEVER use the offset-immediate arg of
// global_load_lds — it corrupts the LDS destination address (added to both
// global and LDS sides). offset=0 + explicit pointer arithmetic only.
#define GLDS(g, l) __builtin_amdgcn_global_load_lds( \
    (const __attribute__((address_space(1))) void*)(g),   \
    (__attribute__((address_space(3))) void*)(l), 16, 0, 0)

// ------------------------------------------------------------------
// Single-segment implicit-GEMM conv job over N=8192, M=128 rows.
// in: NHWC bf16 [8][1024][Cin]; w: packed bf16 rows [128][wstride],
// columns (tap - tap_lo)*Cin + ci. out f32 [n][cout_stride] (+col offset).
// BK=64 path for Cin in {128, 256}; BK=32 path for Cin=16 (l=0 x-seg).
// ------------------------------------------------------------------
struct Seg {
    const unsigned short* in;
    int cl;        // log2(Cin)
    int tap_lo, tap_hi;
    int five;
};
struct Job {
    const unsigned short* w;
    float* out;
    int wstride, cout_stride;
    Seg s;
};
struct Jobs14 { Job j[14]; };
struct Jobs8  { Job j[8]; };

template<typename JOBS>
__global__ __launch_bounds__(256) void conv_mfma_kernel(JOBS jobs, const unsigned short* zp)
{
    __shared__ unsigned short sA[8192];   // 128 rows x 64 K (16 KB)
    __shared__ unsigned short sB[8192];
    const Job jb = jobs.j[blockIdx.y];
    const int tid = threadIdx.x;

    const int rA = tid & 127;
    const int q1 = tid >> 7;            // stages chunks q1+2j, j=0..3 (BK=64)
    const unsigned short* wrow = jb.w + (size_t)rA * jb.wstride + q1 * 8;

    const int ng = blockIdx.x * 128 + rA;
    const int bb = ng >> 10, pp = ng & 1023;
    const int py = pp >> 5, px = pp & 31;

    unsigned short* ldsA[4];
    unsigned short* ldsB[4];
#pragma unroll
    for (int j = 0; j < 4; ++j) {
        ldsA[j] = &sA[(tid + j * 256) * 8];
        ldsB[j] = &sB[(tid + j * 256) * 8];
    }

    const int lane = tid & 63, wv = tid >> 6;
    const int wm = (wv & 1) << 6;
    const int wn = (wv >> 1) << 6;
    const int qq = lane >> 4, rr = lane & 15;

    f4v acc[4][4];
#pragma unroll
    for (int i = 0; i < 4; ++i)
#pragma unroll
        for (int j = 0; j < 4; ++j) acc[i][j] = (f4v)0.f;

    const Seg sg = jb.s;
    const int cil = sg.cl;
    const unsigned short* inb = sg.in + ((size_t)bb << (10 + cil));

    if (cil >= 5) {
        const int cin = 1 << cil;
        for (int tap = sg.tap_lo; tap < sg.tap_hi; ++tap) {
            int dy = 0, dx = 0;
            if (sg.five) { const int t5 = (tap * 52) >> 8; dy = t5 - 2; dx = tap - t5 * 5 - 2; }
            const int yy = py + dy, xx = px + dx;
            const bool ok = ((unsigned)yy < 32u) & ((unsigned)xx < 32u);
            const unsigned short* gB = ok ? (inb + ((((yy << 5) + xx)) << cil) + q1 * 8)
                                          : (zp + q1 * 8);
            const unsigned short* gA = wrow + ((tap - sg.tap_lo) << cil);
            for (int c = 0; c < cin; c += 64) {
#pragma unroll
                for (int j = 0; j < 4; ++j) {
                    GLDS(gA + j * 16, ldsA[j]);
                    GLDS(gB + j * 16, ldsB[j]);
                }
                gA += 64; gB += 64;
                __syncthreads();
#pragma unroll
                for (int hh = 0; hh < 2; ++hh) {
                    const int cb = (hh * 4 + qq) * 128;
                    bf8v av[4], bv[4];
#pragma unroll
                    for (int mi = 0; mi < 4; ++mi)
                        av[mi] = *(const bf8v*)&sA[(cb + wm + mi * 16 + rr) * 8];
#pragma unroll
                    for (int ni = 0; ni < 4; ++ni)
                        bv[ni] = *(const bf8v*)&sB[(cb + wn + ni * 16 + rr) * 8];
#pragma unroll
                    for (int mi = 0; mi < 4; ++mi)
#pragma unroll
                        for (int ni = 0; ni < 4; ++ni)
                            acc[mi][ni] = __builtin_amdgcn_mfma_f32_16x16x32_bf16(
                                av[mi], bv[ni], acc[mi][ni], 0, 0, 0);
                }
                __syncthreads();
            }
        }
    } else {
        // Cin=16 (l=0 x-seg): K = 26*16 = 416, BK=32, per-chunk gather
        for (int k = 0; k < 416; k += 32) {
            const unsigned short* gA = wrow + k;
            GLDS(gA,      ldsA[0]);
            GLDS(gA + 16, ldsA[1]);
#pragma unroll
            for (int cc = 0; cc < 2; ++cc) {
                const int kk = k + q1 * 8 + cc * 16;
                const int tap = kk >> 4;
                const int ci = kk & 15;
                const int t5 = (tap * 52) >> 8;
                const int yy = py + t5 - 2;
                const int xx = px + (tap - t5 * 5) - 2;
                const bool ok = (tap < 25) & ((unsigned)yy < 32u) & ((unsigned)xx < 32u);
                const unsigned short* gp = ok ? (inb + ((((yy << 5) + xx)) << 4) + ci) : zp;
                GLDS(gp, ldsB[cc]);
            }
            __syncthreads();
            {
                const int cb = qq * 128;
                bf8v av[4], bv[4];
#pragma unroll
                for (int mi = 0; mi < 4; ++mi)
                    av[mi] = *(const bf8v*)&sA[(cb + wm + mi * 16 + rr) * 8];
#pragma unroll
                for (int ni = 0; ni < 4; ++ni)
                    bv[ni] = *(const bf8v*)&sB[(cb + wn + ni * 16 + rr) * 8];
#pragma unroll
                for (int mi = 0; mi < 4; ++mi)
#pragma unroll
                    for (int ni = 0; ni < 4; ++ni)
                        acc[mi][ni] = __builtin_amdgcn_mfma_f32_16x16x32_bf16(
                            av[mi], bv[ni], acc[mi][ni], 0, 0, 0);
            }
            __syncthreads();
        }
    }

    // epilogue: col = lane&15 -> n, row = (lane>>4)*4 + reg -> m
    const int nfix = blockIdx.x * 128 + wn;
#pragma unroll
    for (int ni = 0; ni < 4; ++ni) {
        const int n = nfix + ni * 16 + rr;
        float* ob = jb.out + (size_t)n * jb.cout_stride + wm + qq * 4;
#pragma unroll
        for (int mi = 0; mi < 4; ++mi)
            *(f4v*)(ob + mi * 16) = acc[mi][ni];
    }
}

// ------------------------------------------------------------------
__global__ __launch_bounds__(256) void pack_kernel(
    const float* __restrict__ src, unsigned short* __restrict__ dst,
    int cl, int tapsPad, int srcTaps, int dstStride, int dstColOff,
    int dstRowBase, int total)
{
    const int idx = blockIdx.x * 256 + threadIdx.x;
    if (idx >= total) return;
    const int ci = idx & ((1 << cl) - 1);
    const int t2 = idx >> cl;
    const int tap = t2 % tapsPad;
    const int co = t2 / tapsPad;
    float v = 0.f;
    if (tap < srcTaps)
        v = src[((size_t)(co << cl) + ci) * srcTaps + tap];
    dst[(size_t)(dstRowBase + co) * dstStride + dstColOff + (tap << cl) + ci] = f2bf(v);
}

__global__ __launch_bounds__(256) void net_kernel(
    const float* __restrict__ frames, const float* __restrict__ mask,
    const float* __restrict__ xgen, unsigned short* __restrict__ net, int t)
{
    const int idx = blockIdx.x * 256 + threadIdx.x;  // 8192*16
    const int n = idx >> 4, ch = idx & 15;
    const int b = n >> 10, p = n & 1023;
    const float fr = frames[((((size_t)b * 20 + t) << 10) + p) * 16 + ch];
    float v;
    if (t < TPREV) v = fr;
    else {
        const float mk = mask[((((size_t)b * 9 + (t - TPREV)) << 10) + p) * 16 + ch];
        v = mk * fr + (1.f - mk) * xgen[idx];
    }
    net[idx] = f2bf(v);
}

// gates from preA+preB ([n][896] each)
__global__ __launch_bounds__(256) void gates_kernel(
    const float* __restrict__ preA, const float* __restrict__ preB,
    float* __restrict__ c, float* __restrict__ m,
    unsigned short* __restrict__ m_bf, unsigned short* __restrict__ mem)
{
    const int idx = blockIdx.x * 256 + threadIdx.x;  // 8192*128
    const int n = idx >> 7, ch = idx & 127;
    const float* pa = preA + (size_t)n * 896 + ch;
    const float* pb = preB + (size_t)n * 896 + ch;
    const float i_ = pa[0]   + pb[0];
    const float f_ = pa[128] + pb[128];
    const float g_ = pa[256] + pb[256];
    const float ip = pa[384] + pb[384];
    const float fp = pa[512] + pb[512];
    const float gp = pa[640] + pb[640];
    const float cn = sigmoidf_(f_ + 1.f) * c[idx] + sigmoidf_(i_) * tanhf(g_);
    const float mn = sigmoidf_(fp + 1.f) * m[idx] + sigmoidf_(ip) * tanhf(gp);
    c[idx] = cn;
    m[idx] = mn;
    m_bf[idx] = f2bf(mn);
    mem[(size_t)n * 256 + ch] = f2bf(cn);
    mem[(size_t)n * 256 + 128 + ch] = f2bf(mn);
}

__global__ __launch_bounds__(256) void hout_kernel(
    const float* __restrict__ preA, const float* __restrict__ preB,
    const float* __restrict__ opart, const float* __restrict__ lconv,
    unsigned short* __restrict__ h)
{
    const int idx = blockIdx.x * 256 + threadIdx.x;  // 8192*128
    const int n = idx >> 7, ch = idx & 127;
    float oc = preA[(size_t)n * 896 + 768 + ch] + preB[(size_t)n * 896 + 768 + ch];
#pragma unroll
    for (int j = 0; j < 7; ++j) oc += opart[idx + (size_t)j * 1048576];
    h[idx] = f2bf(sigmoidf_(oc) * tanhf(lconv[idx]));
}

__global__ __launch_bounds__(256) void wout_kernel(
    const unsigned short* __restrict__ h3, const float* __restrict__ wo,
    float* __restrict__ xgen, float* __restrict__ out, int t)
{
    const int idx = blockIdx.x * 256 + threadIdx.x;  // 8192*16
    const int n = idx >> 4, ch = idx & 15;
    const int b = n >> 10, p = n & 1023;
    const unsigned short* hr = h3 + (size_t)n * 128;
    const float* wr = wo + ch * 128;
    float acc = 0.f;
#pragma unroll 8
    for (int ci = 0; ci < 128; ++ci)
        acc = fmaf(bf2f(hr[ci]), wr[ci], acc);
    xgen[idx] = acc;
    out[((((size_t)b * TT + t) << 10) + p) * 16 + ch] = acc;
}

extern "C" void kernel_launch(void* const* d_in, const int* in_sizes, int n_in,
                              void* d_out, int out_size, void* d_ws, size_t ws_size,
                              hipStream_t stream)
{
    const float* frames = (const float*)d_in[0];
    const float* mask   = (const float*)d_in[1];
    const float* Wx0    = (const float*)d_in[2];
    const float* Wx     = (const float*)d_in[3];
    const float* Wh     = (const float*)d_in[4];
    const float* Wm     = (const float*)d_in[5];
    const float* Wo     = (const float*)d_in[6];
    const float* Wl     = (const float*)d_in[7];
    const float* Wout   = (const float*)d_in[8];
    float* out = (float*)d_out;

    char* base = (char*)d_ws;
    size_t off = 0;
    auto take = [&](size_t bytes) -> char* {
        char* p = base + off;
        off = (off + bytes + 255) & ~(size_t)255;
        return p;
    };
    // ---- zero-init region ----
    float* c0            = (float*)take(4ull * 1048576 * 4);
    float* m32           = (float*)take((size_t)1048576 * 4);
    unsigned short* hbf  = (unsigned short*)take(4ull * 1048576 * 2);
    unsigned short* mbf  = (unsigned short*)take((size_t)1048576 * 2);
    unsigned short* zp   = (unsigned short*)take(1024);
    const size_t zbytes = off;
    // ---- working buffers ----
    float* xgen          = (float*)take((size_t)131072 * 4);
    float* preA          = (float*)take((size_t)8192 * 896 * 4);
    float* preB          = (float*)take((size_t)8192 * 896 * 4);
    float* lconv         = (float*)take((size_t)1048576 * 4);
    float* opart         = (float*)take(7ull * 1048576 * 4);
    unsigned short* net  = (unsigned short*)take((size_t)131072 * 2);
    unsigned short* mem  = (unsigned short*)take((size_t)2097152 * 2);
    // ---- packed weights: PA[l]: [896][K_l], K_0 = 416+3200, else 6400 ----
    unsigned short* pa0  = (unsigned short*)take((size_t)896 * 3616 * 2);
    unsigned short* pa1  = (unsigned short*)take((size_t)896 * 6400 * 2);
    unsigned short* pa2  = (unsigned short*)take((size_t)896 * 6400 * 2);
    unsigned short* pa3  = (unsigned short*)take((size_t)896 * 6400 * 2);
    unsigned short* pal[4] = { pa0, pa1, pa2, pa3 };
    unsigned short* wop  = (unsigned short*)take(4ull * 128 * 6400 * 2);
    unsigned short* wlp  = (unsigned short*)take(4ull * 128 * 256 * 2);

    hipMemsetAsync(d_ws, 0, zbytes, stream);

    auto pack = [&](const float* s, unsigned short* d, int Co, int cl, int tapsPad,
                    int srcTaps, int stride, int colOff, int rowBase) {
        const int total = (Co * tapsPad) << cl;
        pack_kernel<<<(total + 255) / 256, 256, 0, stream>>>(
            s, d, cl, tapsPad, srcTaps, stride, colOff, rowBase, total);
    };
    pack(Wx0, pa0, 896, 4, 26, 25, 3616, 0, 0);
    for (int l = 1; l < 4; ++l)
        pack(Wx + (size_t)(l - 1) * 896 * 128 * 25, pal[l], 896, 7, 25, 25, 6400, 0, 0);
    for (int l = 0; l < 4; ++l) {
        const int Kl = (l == 0) ? 3616 : 6400;
        const int Kx = (l == 0) ? 416 : 3200;
        const float* whl = Wh + (size_t)l * 512 * 128 * 25;
        pack(whl, pal[l], 384, 7, 25, 25, Kl, Kx, 0);
        pack(whl + (size_t)384 * 128 * 25, pal[l], 128, 7, 25, 25, Kl, Kx, 768);
        pack(Wm + (size_t)l * 384 * 128 * 25, pal[l], 384, 7, 25, 25, Kl, Kx, 384);
        pack(Wo + (size_t)l * 128 * 256 * 25, wop + (size_t)l * 819200, 128, 8, 25, 25, 6400, 0, 0);
        pack(Wl + (size_t)l * 128 * 256, wlp + (size_t)l * 32768, 128, 8, 1, 1, 256, 0, 0);
    }

    const int ts[8] = {0, 4, 8, 12, 16, 19, 22, 25};

    for (int t = 0; t < TT; ++t) {
        net_kernel<<<512, 256, 0, stream>>>(frames, mask, xgen, net, t);
        for (int l = 0; l < 4; ++l) {
            const unsigned short* xin = (l == 0) ? net : (hbf + (size_t)(l - 1) * 1048576);
            const int clx = (l == 0) ? 4 : 7;
            const int Kl = (l == 0) ? 3616 : 6400;
            const int Kx = (l == 0) ? 416 : 3200;
            unsigned short* hl = hbf + (size_t)l * 1048576;

            // ---- phase A: 14 split-K jobs (7 x-seg -> preA, 7 h/m-seg -> preB)
            Jobs14 J{};
            for (int g = 0; g < 7; ++g) {
                J.j[g] = Job{ pal[l] + (size_t)g * 128 * Kl, preA + g * 128,
                              Kl, 896, Seg{ xin, clx, 0, 25, 1 } };
                const unsigned short* sec = (g < 3 || g == 6) ? hl : mbf;
                J.j[7 + g] = Job{ pal[l] + (size_t)g * 128 * Kl + Kx, preB + g * 128,
                                  Kl, 896, Seg{ sec, 7, 0, 25, 1 } };
            }
            conv_mfma_kernel<Jobs14><<<dim3(64, 14), 256, 0, stream>>>(J, zp);

            gates_kernel<<<4096, 256, 0, stream>>>(preA, preB,
                c0 + (size_t)l * 1048576, m32, mbf, mem);

            // ---- phase B: oconv split-K x7 + lconv
            Jobs8 JB{};
            for (int s = 0; s < 7; ++s)
                JB.j[s] = Job{ wop + (size_t)l * 819200 + (ts[s] << 8), opart + (size_t)s * 1048576,
                               6400, 128, Seg{ mem, 8, ts[s], ts[s + 1], 1 } };
            JB.j[7] = Job{ wlp + (size_t)l * 32768, lconv, 256, 128,
                           Seg{ mem, 8, 0, 1, 0 } };
            conv_mfma_kernel<Jobs8><<<dim3(64, 8), 256, 0, stream>>>(JB, zp);

            hout_kernel<<<4096, 256, 0, stream>>>(preA, preB, opart, lconv, hl);
        }
        wout_kernel<<<512, 256, 0, stream>>>(hbf + (size_t)3 * 1048576, Wout, xgen, out, t);
    }
}

// Round 7
// 13170.380 us; speedup vs baseline: 1.4817x; 1.4817x over previous
//
#include <hip/hip_runtime.h>
#include <math.h>

#define TT 19
#define TPREV 10

typedef __attribute__((ext_vector_type(8))) short bf8v;
typedef __attribute__((ext_vector_type(4))) float f4v;

__device__ __forceinline__ float sigmoidf_(float x){ return 1.f/(1.f+expf(-x)); }
__device__ __forceinline__ unsigned short f2bf(float x){
    unsigned int u = __float_as_uint(x);
    u += 0x7FFFu + ((u>>16)&1u);
    return (unsigned short)(u>>16);
}
__device__ __forceinline__ float bf2f(unsigned short b){ return __uint_as_float(((unsigned int)b)<<16); }

// RULE (R4, keep forever): NEVER use the offset-immediate arg of
// global_load_lds — it corrupts the LDS destination address. offset=0 +
// explicit pointer arithmetic only.
#define GLDS(g, l) __builtin_amdgcn_global_load_lds( \
    (const __attribute__((address_space(1))) void*)(g),   \
    (__attribute__((address_space(3))) void*)(l), 16, 0, 0)

// ------------------------------------------------------------------
// Halo-LDS implicit-GEMM conv. N-tile = 128 pixels (4 rows), M = 128.
// Stream segs (cl>=5): weights pre-packed as linear 8KB tiles
//   [at = ch*ntaps + t][q 0..3][row 0..127][8], consumed with 1-tile-ahead
//   GLDS prefetch (double buffer). Activations staged once per 32-ci chunk
//   into a padded halo (8r x 40c x stride40), taps read from LDS.
// cl==4 seg (l=0 x-input): R5-proven BK=32 gather path (w4/416 layout).
// ------------------------------------------------------------------
struct HSeg {
    const unsigned short* in;
    int cl;        // log2(Cin); 4 -> gather path
    int c0;        // absolute ci base of this seg's chunks
    int nch;       // number of 32-ci chunks
    int tap0, ntaps, five;
};
struct HJob {
    const unsigned short* wt;   // tile stream
    const unsigned short* w4;   // cl4 gather weights ([row][416]) or null
    float* out;
    int cout_stride, nseg;
    HSeg s[2];
};
struct HJobs7 { HJob j[7]; };
struct HJobs9 { HJob j[9]; };

template<typename JOBS>
__global__ __launch_bounds__(256) void hconv_kernel(JOBS jobs, const unsigned short* zp)
{
    __shared__ unsigned short sA[8192];    // 2 x 8KB tile buffers
    __shared__ unsigned short sH[12800];   // halo 8x40 x stride40 (25.6 KB)
    const HJob jb = jobs.j[blockIdx.y];
    const int tid = threadIdx.x;

    const int rA = tid & 127;
    const int q1 = tid >> 7;

    const int ng0 = blockIdx.x * 128;
    const int bb = ng0 >> 10, p0 = ng0 & 1023;
    const int y0 = p0 >> 5;
    const int py = y0 + ((tid & 127) >> 5);  // unused helper kept minimal

    const int lane = tid & 63, wv = tid >> 6;
    const int wm = (wv & 1) << 6;
    const int wn = (wv >> 1) << 6;
    const int qq = lane >> 4, rr = lane & 15;

    // per-lane halo read bases (tap-independent)
    int bofs0[4];
#pragma unroll
    for (int ni = 0; ni < 4; ++ni) {
        const int ln = wn + ni * 16 + rr;
        bofs0[ni] = (((ln >> 5) + 2) * 40 + (ln & 31) + 4) * 40 + qq * 8;
    }

    f4v acc[4][4];
#pragma unroll
    for (int i = 0; i < 4; ++i)
#pragma unroll
        for (int j = 0; j < 4; ++j) acc[i][j] = (f4v)0.f;

    const unsigned short* wptr = jb.wt;
    int buf = 0;
    bool first = true;

    for (int si = 0; si < jb.nseg; ++si) {
        const HSeg sg = jb.s[si];
        if (sg.cl == 4) {
            // ---- R5-proven gather path (Cin=16, K=416, BK=32) ----
            const unsigned short* wrow4 = jb.w4 + (size_t)rA * 416 + q1 * 8;
            const unsigned short* inb4 = sg.in + ((size_t)bb << 14);
            const int pyy = y0 + (rA >> 5), pxx = rA & 31;
            for (int k = 0; k < 416; k += 32) {
                const unsigned short* gA = wrow4 + k;
                GLDS(gA,      &sA[tid * 8]);
                GLDS(gA + 16, &sA[(tid + 256) * 8]);
#pragma unroll
                for (int cc = 0; cc < 2; ++cc) {
                    const int kk = k + q1 * 8 + cc * 16;
                    const int tap = kk >> 4;
                    const int ci = kk & 15;
                    const int t5 = (tap * 52) >> 8;
                    const int yy = pyy + t5 - 2;
                    const int xx = pxx + (tap - t5 * 5) - 2;
                    const bool ok = (tap < 25) & ((unsigned)yy < 32u) & ((unsigned)xx < 32u);
                    const unsigned short* gp = ok ? (inb4 + ((((yy << 5) + xx)) << 4) + ci) : zp;
                    GLDS(gp, cc ? &sH[(tid + 256) * 8] : &sH[tid * 8]);
                }
                __syncthreads();
                {
                    const int cb = qq * 128;
                    bf8v av[4], bv[4];
#pragma unroll
                    for (int mi = 0; mi < 4; ++mi)
                        av[mi] = *(const bf8v*)&sA[(cb + wm + mi * 16 + rr) * 8];
#pragma unroll
                    for (int ni = 0; ni < 4; ++ni)
                        bv[ni] = *(const bf8v*)&sH[(cb + wn + ni * 16 + rr) * 8];
#pragma unroll
                    for (int mi = 0; mi < 4; ++mi)
#pragma unroll
                        for (int ni = 0; ni < 4; ++ni)
                            acc[mi][ni] = __builtin_amdgcn_mfma_f32_16x16x32_bf16(
                                av[mi], bv[ni], acc[mi][ni], 0, 0, 0);
                }
                __syncthreads();
            }
            continue;
        }
        // ---- stream path ----
        const unsigned short* inb = sg.in + ((size_t)bb << (10 + sg.cl));
        for (int ch = 0; ch < sg.nch; ++ch) {
            const int c0 = sg.c0 + ch * 32;
            // stage halo: 1280 slots of 16B, 5 per thread
#pragma unroll
            for (int k = 0; k < 5; ++k) {
                const int s = tid + k * 256;
                const int r = s / 160;
                const int rem = s - r * 160;
                const int cc = rem >> 2, G = rem & 3;
                const int y = y0 + r - 2, x = cc - 4;
                const bool okv = ((unsigned)y < 32u) & ((unsigned)x < 32u);
                const int yc = okv ? y : 0, xc = okv ? x : 0;
                bf8v v = *(const bf8v*)(inb + ((((yc << 5) + xc)) << sg.cl) + c0 + G * 8);
                if (!okv) v = (bf8v)(short)0;
                *(bf8v*)&sH[(r * 40 + cc) * 40 + G * 8] = v;
            }
            if (first) {
                GLDS(wptr + tid * 8,         &sA[tid * 8]);
                GLDS(wptr + (tid + 256) * 8, &sA[(tid + 256) * 8]);
                wptr += 4096;
                first = false;
            }
            __syncthreads();
            for (int t = 0; t < sg.ntaps; ++t) {
                // prefetch next tile into buf^1 (consumed right after barrier)
                GLDS(wptr + tid * 8,         &sA[(buf ^ 1) * 4096 + tid * 8]);
                GLDS(wptr + (tid + 256) * 8, &sA[(buf ^ 1) * 4096 + (tid + 256) * 8]);
                wptr += 4096;
                int tapofs = 0;
                if (sg.five) {
                    const int tap = sg.tap0 + t;
                    const int t5 = (tap * 52) >> 8;
                    tapofs = ((t5 - 2) * 40 + (tap - t5 * 5 - 2)) * 40;
                }
                bf8v av[4], bv[4];
#pragma unroll
                for (int mi = 0; mi < 4; ++mi)
                    av[mi] = *(const bf8v*)&sA[buf * 4096 + (qq * 128 + wm + mi * 16 + rr) * 8];
#pragma unroll
                for (int ni = 0; ni < 4; ++ni)
                    bv[ni] = *(const bf8v*)&sH[bofs0[ni] + tapofs];
#pragma unroll
                for (int mi = 0; mi < 4; ++mi)
#pragma unroll
                    for (int ni = 0; ni < 4; ++ni)
                        acc[mi][ni] = __builtin_amdgcn_mfma_f32_16x16x32_bf16(
                            av[mi], bv[ni], acc[mi][ni], 0, 0, 0);
                __syncthreads();
                buf ^= 1;
            }
        }
    }

    // epilogue: col = lane&15 -> n, row = (lane>>4)*4 + reg -> m
    const int nfix = ng0 + wn;
#pragma unroll
    for (int ni = 0; ni < 4; ++ni) {
        const int n = nfix + ni * 16 + rr;
        float* ob = jb.out + (size_t)n * jb.cout_stride + wm + qq * 4;
#pragma unroll
        for (int mi = 0; mi < 4; ++mi)
            *(f4v*)(ob + mi * 16) = acc[mi][ni];
    }
}

// ------------------------------------------------------------------
// packT: OIHW f32 -> linear tile stream [at][q][row][8] bf16
// at = ch*ntaps + t; ci = ci0 + ch*32 + q*8 + j; tap = tap0 + t
// ------------------------------------------------------------------
__global__ __launch_bounds__(256) void packT_kernel(
    const float* __restrict__ src, unsigned short* __restrict__ dst,
    int Cin, int srcTaps, int rowOff, int ci0, int ntaps, int tap0, int total)
{
    const int idx = blockIdx.x * 256 + threadIdx.x;
    if (idx >= total) return;
    const int j = idx & 7;
    const int row = (idx >> 3) & 127;
    const int q = (idx >> 10) & 3;
    const int at = idx >> 12;
    const int ch = at / ntaps;
    const int tap = tap0 + (at - ch * ntaps);
    const int ci = ci0 + ch * 32 + q * 8 + j;
    const float v = src[((size_t)(rowOff + row) * Cin + ci) * srcTaps + tap];
    dst[idx] = f2bf(v);
}

// old row-major pack for the l=0 cl4 gather blob ([row][tap*16+ci], taps pad 26)
__global__ __launch_bounds__(256) void pack4_kernel(
    const float* __restrict__ src, unsigned short* __restrict__ dst, int total)
{
    const int idx = blockIdx.x * 256 + threadIdx.x;
    if (idx >= total) return;
    const int ci = idx & 15;
    const int t2 = idx >> 4;
    const int tap = t2 % 26;
    const int co = t2 / 26;
    float v = 0.f;
    if (tap < 25)
        v = src[((size_t)(co << 4) + ci) * 25 + tap];
    dst[idx] = f2bf(v);
}

__global__ __launch_bounds__(256) void net_kernel(
    const float* __restrict__ frames, const float* __restrict__ mask,
    const float* __restrict__ xgen, unsigned short* __restrict__ net, int t)
{
    const int idx = blockIdx.x * 256 + threadIdx.x;  // 8192*16
    const int n = idx >> 4, ch = idx & 15;
    const int b = n >> 10, p = n & 1023;
    const float fr = frames[((((size_t)b * 20 + t) << 10) + p) * 16 + ch];
    float v;
    if (t < TPREV) v = fr;
    else {
        const float mk = mask[((((size_t)b * 9 + (t - TPREV)) << 10) + p) * 16 + ch];
        v = mk * fr + (1.f - mk) * xgen[idx];
    }
    net[idx] = f2bf(v);
}

__global__ __launch_bounds__(256) void gates_kernel(
    const float* __restrict__ pre, float* __restrict__ c, float* __restrict__ m,
    unsigned short* __restrict__ m_bf, unsigned short* __restrict__ mem)
{
    const int idx = blockIdx.x * 256 + threadIdx.x;  // 8192*128
    const int n = idx >> 7, ch = idx & 127;
    const float* pn = pre + (size_t)n * 896 + ch;
    const float i_ = pn[0];
    const float f_ = pn[128];
    const float g_ = pn[256];
    const float ip = pn[384];
    const float fp = pn[512];
    const float gp = pn[640];
    const float cn = sigmoidf_(f_ + 1.f) * c[idx] + sigmoidf_(i_) * tanhf(g_);
    const float mn = sigmoidf_(fp + 1.f) * m[idx] + sigmoidf_(ip) * tanhf(gp);
    c[idx] = cn;
    m[idx] = mn;
    m_bf[idx] = f2bf(mn);
    mem[(size_t)n * 256 + ch] = f2bf(cn);
    mem[(size_t)n * 256 + 128 + ch] = f2bf(mn);
}

__global__ __launch_bounds__(256) void hout_kernel(
    const float* __restrict__ pre, const float* __restrict__ opart,
    const float* __restrict__ lconv, unsigned short* __restrict__ h)
{
    const int idx = blockIdx.x * 256 + threadIdx.x;  // 8192*128
    const int n = idx >> 7, ch = idx & 127;
    float oc = pre[(size_t)n * 896 + 768 + ch];
#pragma unroll
    for (int j = 0; j < 8; ++j) oc += opart[idx + (size_t)j * 1048576];
    h[idx] = f2bf(sigmoidf_(oc) * tanhf(lconv[idx]));
}

__global__ __launch_bounds__(256) void wout_kernel(
    const unsigned short* __restrict__ h3, const float* __restrict__ wo,
    float* __restrict__ xgen, float* __restrict__ out, int t)
{
    const int idx = blockIdx.x * 256 + threadIdx.x;  // 8192*16
    const int n = idx >> 4, ch = idx & 15;
    const int b = n >> 10, p = n & 1023;
    const unsigned short* hr = h3 + (size_t)n * 128;
    const float* wr = wo + ch * 128;
    float acc = 0.f;
#pragma unroll 8
    for (int ci = 0; ci < 128; ++ci)
        acc = fmaf(bf2f(hr[ci]), wr[ci], acc);
    xgen[idx] = acc;
    out[((((size_t)b * TT + t) << 10) + p) * 16 + ch] = acc;
}

extern "C" void kernel_launch(void* const* d_in, const int* in_sizes, int n_in,
                              void* d_out, int out_size, void* d_ws, size_t ws_size,
                              hipStream_t stream)
{
    const float* frames = (const float*)d_in[0];
    const float* mask   = (const float*)d_in[1];
    const float* Wx0    = (const float*)d_in[2];
    const float* Wx     = (const float*)d_in[3];
    const float* Wh     = (const float*)d_in[4];
    const float* Wm     = (const float*)d_in[5];
    const float* Wo     = (const float*)d_in[6];
    const float* Wl     = (const float*)d_in[7];
    const float* Wout   = (const float*)d_in[8];
    float* out = (float*)d_out;

    char* base = (char*)d_ws;
    size_t off = 0;
    auto take = [&](size_t bytes) -> char* {
        char* p = base + off;
        off = (off + bytes + 255) & ~(size_t)255;
        return p;
    };
    // ---- zero-init region ----
    float* c0            = (float*)take(4ull * 1048576 * 4);
    float* m32           = (float*)take((size_t)1048576 * 4);
    unsigned short* hbf  = (unsigned short*)take(4ull * 1048576 * 2);
    unsigned short* mbf  = (unsigned short*)take((size_t)1048576 * 2);
    unsigned short* zp   = (unsigned short*)take(1024);
    const size_t zbytes = off;
    // ---- working buffers ----
    float* xgen          = (float*)take((size_t)131072 * 4);
    float* pre           = (float*)take((size_t)8192 * 896 * 4);
    float* lconv         = (float*)take((size_t)1048576 * 4);
    float* opart         = (float*)take(8ull * 1048576 * 4);
    unsigned short* net  = (unsigned short*)take((size_t)131072 * 2);
    unsigned short* mem  = (unsigned short*)take((size_t)2097152 * 2);
    // ---- packed weights (tile streams; +4096 el pad for prefetch overrun) ----
    unsigned short* pa0x = (unsigned short*)take((size_t)896 * 416 * 2);
    unsigned short* paT0 = (unsigned short*)take(((size_t)7 * 100 * 4096 + 4096) * 2);
    unsigned short* paT1 = (unsigned short*)take(((size_t)7 * 200 * 4096 + 4096) * 2);
    unsigned short* paT2 = (unsigned short*)take(((size_t)7 * 200 * 4096 + 4096) * 2);
    unsigned short* paT3 = (unsigned short*)take(((size_t)7 * 200 * 4096 + 4096) * 2);
    unsigned short* paT[4] = { paT0, paT1, paT2, paT3 };
    unsigned short* oT   = (unsigned short*)take((4ull * 200 * 4096 + 4096) * 2);
    unsigned short* lT   = (unsigned short*)take((4ull * 8 * 4096 + 4096) * 2);

    hipMemsetAsync(d_ws, 0, zbytes, stream);

    auto packT = [&](const float* s, unsigned short* d, int Cin, int srcTaps,
                     int rowOff, int ci0, int nch, int ntaps, int tap0) {
        const int total = nch * ntaps * 4096;
        packT_kernel<<<(total + 255) / 256, 256, 0, stream>>>(
            s, d, Cin, srcTaps, rowOff, ci0, ntaps, tap0, total);
    };
    // l=0 x gather blob
    pack4_kernel<<<(896 * 416 + 255) / 256, 256, 0, stream>>>(Wx0, pa0x, 896 * 416);
    // phase-A streams
    for (int g = 0; g < 7; ++g) {
        // l=0: hm stream only (100 tiles per gate)
        const float* hm0 = (g < 3) ? (Wh + (size_t)g * 128 * 128 * 25)
                         : (g == 6) ? (Wh + (size_t)384 * 128 * 25)
                                    : (Wm + (size_t)(g - 3) * 128 * 128 * 25);
        packT(hm0, paT0 + (size_t)g * 100 * 4096, 128, 25, 0, 0, 4, 25, 0);
        for (int l = 1; l < 4; ++l) {
            packT(Wx + (size_t)(l - 1) * 896 * 128 * 25,
                  paT[l] + (size_t)g * 200 * 4096, 128, 25, g * 128, 0, 4, 25, 0);
            const float* hmsrc = (g < 3) ? (Wh + ((size_t)l * 512 + g * 128) * 128 * 25)
                               : (g == 6) ? (Wh + ((size_t)l * 512 + 384) * 128 * 25)
                                          : (Wm + ((size_t)l * 384 + (g - 3) * 128) * 128 * 25);
            packT(hmsrc, paT[l] + ((size_t)g * 200 + 100) * 4096, 128, 25, 0, 0, 4, 25, 0);
        }
    }
    for (int l = 0; l < 4; ++l) {
        packT(Wo + (size_t)l * 128 * 256 * 25, oT + (size_t)l * 200 * 4096,
              256, 25, 0, 0, 8, 25, 0);
        packT(Wl + (size_t)l * 128 * 256, lT + (size_t)l * 8 * 4096,
              256, 1, 0, 0, 8, 1, 0);
    }

    for (int t = 0; t < TT; ++t) {
        net_kernel<<<512, 256, 0, stream>>>(frames, mask, xgen, net, t);
        for (int l = 0; l < 4; ++l) {
            unsigned short* hl = hbf + (size_t)l * 1048576;
            // ---- phase A: 7 gate jobs (x-seg + h/m-seg accumulated in-reg)
            HJobs7 JA{};
            for (int g = 0; g < 7; ++g) {
                HJob& j = JA.j[g];
                j.out = pre + g * 128;
                j.cout_stride = 896;
                j.nseg = 2;
                const unsigned short* hmsrc = (g < 3 || g == 6) ? hl : mbf;
                if (l == 0) {
                    j.w4 = pa0x + (size_t)g * 128 * 416;
                    j.wt = paT0 + (size_t)g * 100 * 4096;
                    j.s[0] = HSeg{ net, 4, 0, 0, 0, 0, 1 };
                    j.s[1] = HSeg{ hmsrc, 7, 0, 4, 0, 25, 1 };
                } else {
                    j.w4 = nullptr;
                    j.wt = paT[l] + (size_t)g * 200 * 4096;
                    j.s[0] = HSeg{ hbf + (size_t)(l - 1) * 1048576, 7, 0, 4, 0, 25, 1 };
                    j.s[1] = HSeg{ hmsrc, 7, 0, 4, 0, 25, 1 };
                }
            }
            hconv_kernel<HJobs7><<<dim3(64, 7), 256, 0, stream>>>(JA, zp);

            gates_kernel<<<4096, 256, 0, stream>>>(pre, c0 + (size_t)l * 1048576, m32, mbf, mem);

            // ---- phase B: o-conv split by ci-chunk x8 + lconv
            HJobs9 JB{};
            for (int jj = 0; jj < 8; ++jj) {
                HJob& j = JB.j[jj];
                j.wt = oT + ((size_t)l * 200 + jj * 25) * 4096;
                j.w4 = nullptr;
                j.out = opart + (size_t)jj * 1048576;
                j.cout_stride = 128;
                j.nseg = 1;
                j.s[0] = HSeg{ mem, 8, jj * 32, 1, 0, 25, 1 };
            }
            JB.j[8] = HJob{ lT + (size_t)l * 8 * 4096, nullptr, lconv, 128, 1,
                            { HSeg{ mem, 8, 0, 8, 0, 1, 0 }, HSeg{} } };
            hconv_kernel<HJobs9><<<dim3(64, 9), 256, 0, stream>>>(JB, zp);

            hout_kernel<<<4096, 256, 0, stream>>>(pre, opart, lconv, hl);
        }
        wout_kernel<<<512, 256, 0, stream>>>(hbf + (size_t)3 * 1048576, Wout, xgen, out, t);
    }
}

// Round 8
// 13058.388 us; speedup vs baseline: 1.4944x; 1.0086x over previous
//
#include <hip/hip_runtime.h>
#include <math.h>

#define TT 19
#define TPREV 10

typedef __attribute__((ext_vector_type(8))) short bf8v;
typedef __attribute__((ext_vector_type(4))) float f4v;
typedef __attribute__((ext_vector_type(16))) float f16v;

__device__ __forceinline__ float sigmoidf_(float x){ return 1.f/(1.f+expf(-x)); }
__device__ __forceinline__ unsigned short f2bf(float x){
    unsigned int u = __float_as_uint(x);
    u += 0x7FFFu + ((u>>16)&1u);
    return (unsigned short)(u>>16);
}
__device__ __forceinline__ float bf2f(unsigned short b){ return __uint_as_float(((unsigned int)b)<<16); }

// RULE (R4, keep forever): NEVER use the offset-immediate arg of
// global_load_lds — it corrupts the LDS destination address. offset=0 +
// explicit pointer arithmetic only.
#define GLDS(g, l) __builtin_amdgcn_global_load_lds( \
    (const __attribute__((address_space(1))) void*)(g),   \
    (__attribute__((address_space(3))) void*)(l), 16, 0, 0)

// ------------------------------------------------------------------
// Halo-LDS implicit-GEMM conv, 32x32x16 MFMA core.
// Weight tiles: [oct(k/8)][row 0..127][8] bf16, 8KB each, linear stream,
// 1-tile-ahead GLDS prefetch (double buffer). Activations: halo in LDS,
// staged once per 32-ci chunk. cl==4 seg = l0 x-input gather path.
// A layout: lane holds row=lane&31, k=(lane>>5)*8+j  (32x32x16 bf16)
// C/D:      col=lane&31, row=(reg&3)+8*(reg>>2)+4*(lane>>5)
// ------------------------------------------------------------------
struct HSeg {
    const unsigned short* in;
    int cl;        // log2(Cin); 4 -> gather path
    int c0;        // absolute ci base
    int nch;       // number of 32-ci chunks
    int tap0, ntaps, five;
};
struct HJob {
    const unsigned short* wt;   // tile stream
    const unsigned short* w4;   // cl4 gather weights ([row][416]) or unused
    float* out;
    int cout_stride, pad;
    HSeg s;
};
struct HJobs14 { HJob j[14]; };
struct HJobs9  { HJob j[9]; };

template<typename JOBS>
__global__ __launch_bounds__(256) void hconv_kernel(JOBS jobs, const unsigned short* zp)
{
    __shared__ unsigned short sA[8192];    // 2 x 8KB tile buffers
    __shared__ unsigned short sH[12800];   // halo 8x40 cells x stride40
    const HJob jb = jobs.j[blockIdx.y];
    const int tid = threadIdx.x;

    const int rA = tid & 127;
    const int q1 = tid >> 7;

    const int ng0 = blockIdx.x * 128;
    const int bb = ng0 >> 10, p0 = ng0 & 1023;
    const int y0 = p0 >> 5;

    const int lane = tid & 63, wv = tid >> 6;
    const int wm = (wv & 1) << 6;
    const int wn = (wv >> 1) << 6;
    const int col = lane & 31, ll5 = lane >> 5;

    // halo read bases per ni (tap-independent); oct base = ll5
    int bofs0[2];
#pragma unroll
    for (int ni = 0; ni < 2; ++ni) {
        const int ln = wn + ni * 32 + col;
        bofs0[ni] = (((ln >> 5) + 2) * 40 + (ln & 31) + 4) * 40 + ll5 * 8;
    }

    f16v acc[2][2];
#pragma unroll
    for (int i = 0; i < 2; ++i)
#pragma unroll
        for (int j = 0; j < 2; ++j) acc[i][j] = (f16v)0.f;

    const HSeg sg = jb.s;

    if (sg.cl == 4) {
        // ---- gather path (Cin=16, K=416, BK=32) ----
        const unsigned short* wrow4 = jb.w4 + (size_t)rA * 416 + q1 * 8;
        const unsigned short* inb4 = sg.in + ((size_t)bb << 14);
        const int pyy = y0 + (rA >> 5), pxx = rA & 31;
        for (int k = 0; k < 416; k += 32) {
            const unsigned short* gA = wrow4 + k;
            GLDS(gA,      &sA[tid * 8]);
            GLDS(gA + 16, &sA[(tid + 256) * 8]);
#pragma unroll
            for (int cc = 0; cc < 2; ++cc) {
                const int kk = k + q1 * 8 + cc * 16;
                const int tap = kk >> 4;
                const int ci = kk & 15;
                const int t5 = (tap * 52) >> 8;
                const int yy = pyy + t5 - 2;
                const int xx = pxx + (tap - t5 * 5) - 2;
                const bool ok = (tap < 25) & ((unsigned)yy < 32u) & ((unsigned)xx < 32u);
                const unsigned short* gp = ok ? (inb4 + ((((yy << 5) + xx)) << 4) + ci) : zp;
                GLDS(gp, cc ? &sH[(tid + 256) * 8] : &sH[tid * 8]);
            }
            __syncthreads();
#pragma unroll
            for (int s = 0; s < 2; ++s) {
                const int o = s * 2 + ll5;
                bf8v av[2], bv[2];
#pragma unroll
                for (int mi = 0; mi < 2; ++mi)
                    av[mi] = *(const bf8v*)&sA[(o * 128 + wm + mi * 32 + col) * 8];
#pragma unroll
                for (int ni = 0; ni < 2; ++ni)
                    bv[ni] = *(const bf8v*)&sH[(o * 128 + wn + ni * 32 + col) * 8];
#pragma unroll
                for (int mi = 0; mi < 2; ++mi)
#pragma unroll
                    for (int ni = 0; ni < 2; ++ni)
                        acc[mi][ni] = __builtin_amdgcn_mfma_f32_32x32x16_bf16(
                            av[mi], bv[ni], acc[mi][ni], 0, 0, 0);
            }
            __syncthreads();
        }
    } else {
        // ---- stream path ----
        const unsigned short* inb = sg.in + ((size_t)bb << (10 + sg.cl));
        const unsigned short* wptr = jb.wt;
        int buf = 0;
        bool first = true;
        for (int ch = 0; ch < sg.nch; ++ch) {
            const int c0 = sg.c0 + ch * 32;
            // stage halo: 1280 slots of 16B, 5 per thread
#pragma unroll
            for (int k = 0; k < 5; ++k) {
                const int s = tid + k * 256;
                const int r = s / 160;
                const int rem = s - r * 160;
                const int cc = rem >> 2, G = rem & 3;
                const int y = y0 + r - 2, x = cc - 4;
                const bool okv = ((unsigned)y < 32u) & ((unsigned)x < 32u);
                const int yc = okv ? y : 0, xc = okv ? x : 0;
                bf8v v = *(const bf8v*)(inb + ((((yc << 5) + xc)) << sg.cl) + c0 + G * 8);
                if (!okv) v = (bf8v)(short)0;
                *(bf8v*)&sH[(r * 40 + cc) * 40 + G * 8] = v;
            }
            if (first) {
                GLDS(wptr + tid * 8,         &sA[tid * 8]);
                GLDS(wptr + (tid + 256) * 8, &sA[(tid + 256) * 8]);
                wptr += 4096;
                first = false;
            }
            __syncthreads();
            for (int t = 0; t < sg.ntaps; ++t) {
                // prefetch next tile into buf^1
                GLDS(wptr + tid * 8,         &sA[(buf ^ 1) * 4096 + tid * 8]);
                GLDS(wptr + (tid + 256) * 8, &sA[(buf ^ 1) * 4096 + (tid + 256) * 8]);
                wptr += 4096;
                int tapofs = 0;
                if (sg.five) {
                    const int tap = sg.tap0 + t;
                    const int t5 = (tap * 52) >> 8;
                    tapofs = ((t5 - 2) * 40 + (tap - t5 * 5 - 2)) * 40;
                }
                const unsigned short* sAb = &sA[buf * 4096];
#pragma unroll
                for (int s = 0; s < 2; ++s) {
                    const int o = s * 2 + ll5;
                    bf8v av[2], bv[2];
#pragma unroll
                    for (int mi = 0; mi < 2; ++mi)
                        av[mi] = *(const bf8v*)&sAb[(o * 128 + wm + mi * 32 + col) * 8];
#pragma unroll
                    for (int ni = 0; ni < 2; ++ni)
                        bv[ni] = *(const bf8v*)&sH[bofs0[ni] + tapofs + s * 16];
#pragma unroll
                    for (int mi = 0; mi < 2; ++mi)
#pragma unroll
                        for (int ni = 0; ni < 2; ++ni)
                            acc[mi][ni] = __builtin_amdgcn_mfma_f32_32x32x16_bf16(
                                av[mi], bv[ni], acc[mi][ni], 0, 0, 0);
                }
                __syncthreads();
                buf ^= 1;
            }
        }
    }

    // epilogue (32x32 C/D): col=lane&31, row=(reg&3)+8*(reg>>2)+4*ll5
    const int nfix = ng0 + wn + col;
#pragma unroll
    for (int ni = 0; ni < 2; ++ni) {
        const int n = nfix + ni * 32;
        float* ob = jb.out + (size_t)n * jb.cout_stride;
#pragma unroll
        for (int mi = 0; mi < 2; ++mi) {
            const int mb = wm + mi * 32 + 4 * ll5;
            const f16v a = acc[mi][ni];
#pragma unroll
            for (int qd = 0; qd < 4; ++qd) {
                f4v v;
                v[0] = a[qd * 4 + 0]; v[1] = a[qd * 4 + 1];
                v[2] = a[qd * 4 + 2]; v[3] = a[qd * 4 + 3];
                *(f4v*)(ob + mb + qd * 8) = v;
            }
        }
    }
}

// ------------------------------------------------------------------
// packT: OIHW f32 -> linear tile stream [at][oct][row][8] bf16
// ------------------------------------------------------------------
__global__ __launch_bounds__(256) void packT_kernel(
    const float* __restrict__ src, unsigned short* __restrict__ dst,
    int Cin, int srcTaps, int rowOff, int ci0, int ntaps, int tap0, int total)
{
    const int idx = blockIdx.x * 256 + threadIdx.x;
    if (idx >= total) return;
    const int j = idx & 7;
    const int row = (idx >> 3) & 127;
    const int q = (idx >> 10) & 3;
    const int at = idx >> 12;
    const int ch = at / ntaps;
    const int tap = tap0 + (at - ch * ntaps);
    const int ci = ci0 + ch * 32 + q * 8 + j;
    const float v = src[((size_t)(rowOff + row) * Cin + ci) * srcTaps + tap];
    dst[idx] = f2bf(v);
}

__global__ __launch_bounds__(256) void pack4_kernel(
    const float* __restrict__ src, unsigned short* __restrict__ dst, int total)
{
    const int idx = blockIdx.x * 256 + threadIdx.x;
    if (idx >= total) return;
    const int ci = idx & 15;
    const int t2 = idx >> 4;
    const int tap = t2 % 26;
    const int co = t2 / 26;
    float v = 0.f;
    if (tap < 25)
        v = src[((size_t)(co << 4) + ci) * 25 + tap];
    dst[idx] = f2bf(v);
}

__global__ __launch_bounds__(256) void net_kernel(
    const float* __restrict__ frames, const float* __restrict__ mask,
    const float* __restrict__ xgen, unsigned short* __restrict__ net, int t)
{
    const int idx = blockIdx.x * 256 + threadIdx.x;  // 8192*16
    const int n = idx >> 4, ch = idx & 15;
    const int b = n >> 10, p = n & 1023;
    const float fr = frames[((((size_t)b * 20 + t) << 10) + p) * 16 + ch];
    float v;
    if (t < TPREV) v = fr;
    else {
        const float mk = mask[((((size_t)b * 9 + (t - TPREV)) << 10) + p) * 16 + ch];
        v = mk * fr + (1.f - mk) * xgen[idx];
    }
    net[idx] = f2bf(v);
}

__global__ __launch_bounds__(256) void gates_kernel(
    const float* __restrict__ preA, const float* __restrict__ preB,
    float* __restrict__ c, float* __restrict__ m,
    unsigned short* __restrict__ m_bf, unsigned short* __restrict__ mem)
{
    const int idx = blockIdx.x * 256 + threadIdx.x;  // 8192*128
    const int n = idx >> 7, ch = idx & 127;
    const float* pa = preA + (size_t)n * 896 + ch;
    const float* pb = preB + (size_t)n * 896 + ch;
    const float i_ = pa[0]   + pb[0];
    const float f_ = pa[128] + pb[128];
    const float g_ = pa[256] + pb[256];
    const float ip = pa[384] + pb[384];
    const float fp = pa[512] + pb[512];
    const float gp = pa[640] + pb[640];
    const float cn = sigmoidf_(f_ + 1.f) * c[idx] + sigmoidf_(i_) * tanhf(g_);
    const float mn = sigmoidf_(fp + 1.f) * m[idx] + sigmoidf_(ip) * tanhf(gp);
    c[idx] = cn;
    m[idx] = mn;
    m_bf[idx] = f2bf(mn);
    mem[(size_t)n * 256 + ch] = f2bf(cn);
    mem[(size_t)n * 256 + 128 + ch] = f2bf(mn);
}

__global__ __launch_bounds__(256) void hout_kernel(
    const float* __restrict__ preA, const float* __restrict__ preB,
    const float* __restrict__ opart, const float* __restrict__ lconv,
    unsigned short* __restrict__ h)
{
    const int idx = blockIdx.x * 256 + threadIdx.x;  // 8192*128
    const int n = idx >> 7, ch = idx & 127;
    float oc = preA[(size_t)n * 896 + 768 + ch] + preB[(size_t)n * 896 + 768 + ch];
#pragma unroll
    for (int j = 0; j < 8; ++j) oc += opart[idx + (size_t)j * 1048576];
    h[idx] = f2bf(sigmoidf_(oc) * tanhf(lconv[idx]));
}

__global__ __launch_bounds__(256) void wout_kernel(
    const unsigned short* __restrict__ h3, const float* __restrict__ wo,
    float* __restrict__ xgen, float* __restrict__ out, int t)
{
    const int idx = blockIdx.x * 256 + threadIdx.x;  // 8192*16
    const int n = idx >> 4, ch = idx & 15;
    const int b = n >> 10, p = n & 1023;
    const unsigned short* hr = h3 + (size_t)n * 128;
    const float* wr = wo + ch * 128;
    float acc = 0.f;
#pragma unroll 8
    for (int ci = 0; ci < 128; ++ci)
        acc = fmaf(bf2f(hr[ci]), wr[ci], acc);
    xgen[idx] = acc;
    out[((((size_t)b * TT + t) << 10) + p) * 16 + ch] = acc;
}

extern "C" void kernel_launch(void* const* d_in, const int* in_sizes, int n_in,
                              void* d_out, int out_size, void* d_ws, size_t ws_size,
                              hipStream_t stream)
{
    const float* frames = (const float*)d_in[0];
    const float* mask   = (const float*)d_in[1];
    const float* Wx0    = (const float*)d_in[2];
    const float* Wx     = (const float*)d_in[3];
    const float* Wh     = (const float*)d_in[4];
    const float* Wm     = (const float*)d_in[5];
    const float* Wo     = (const float*)d_in[6];
    const float* Wl     = (const float*)d_in[7];
    const float* Wout   = (const float*)d_in[8];
    float* out = (float*)d_out;

    char* base = (char*)d_ws;
    size_t off = 0;
    auto take = [&](size_t bytes) -> char* {
        char* p = base + off;
        off = (off + bytes + 255) & ~(size_t)255;
        return p;
    };
    // ---- zero-init region ----
    float* c0            = (float*)take(4ull * 1048576 * 4);
    float* m32           = (float*)take((size_t)1048576 * 4);
    unsigned short* hbf  = (unsigned short*)take(4ull * 1048576 * 2);
    unsigned short* mbf  = (unsigned short*)take((size_t)1048576 * 2);
    unsigned short* zp   = (unsigned short*)take(1024);
    const size_t zbytes = off;
    // ---- working buffers ----
    float* xgen          = (float*)take((size_t)131072 * 4);
    float* preA          = (float*)take((size_t)8192 * 896 * 4);
    float* preB          = (float*)take((size_t)8192 * 896 * 4);
    float* lconv         = (float*)take((size_t)1048576 * 4);
    float* opart         = (float*)take(8ull * 1048576 * 4);
    unsigned short* net  = (unsigned short*)take((size_t)131072 * 2);
    unsigned short* mem  = (unsigned short*)take((size_t)2097152 * 2);
    // ---- packed weights (tile streams; +4096 el pad for prefetch overrun) ----
    unsigned short* pa0x = (unsigned short*)take((size_t)896 * 416 * 2);
    unsigned short* paT0 = (unsigned short*)take(((size_t)7 * 100 * 4096 + 4096) * 2);
    unsigned short* paT1 = (unsigned short*)take(((size_t)7 * 200 * 4096 + 4096) * 2);
    unsigned short* paT2 = (unsigned short*)take(((size_t)7 * 200 * 4096 + 4096) * 2);
    unsigned short* paT3 = (unsigned short*)take(((size_t)7 * 200 * 4096 + 4096) * 2);
    unsigned short* paT[4] = { paT0, paT1, paT2, paT3 };
    unsigned short* oT   = (unsigned short*)take((4ull * 200 * 4096 + 4096) * 2);
    unsigned short* lT   = (unsigned short*)take((4ull * 8 * 4096 + 4096) * 2);

    hipMemsetAsync(d_ws, 0, zbytes, stream);

    auto packT = [&](const float* s, unsigned short* d, int Cin, int srcTaps,
                     int rowOff, int ci0, int nch, int ntaps, int tap0) {
        const int total = nch * ntaps * 4096;
        packT_kernel<<<(total + 255) / 256, 256, 0, stream>>>(
            s, d, Cin, srcTaps, rowOff, ci0, ntaps, tap0, total);
    };
    pack4_kernel<<<(896 * 416 + 255) / 256, 256, 0, stream>>>(Wx0, pa0x, 896 * 416);
    for (int g = 0; g < 7; ++g) {
        const float* hm0 = (g < 3) ? (Wh + (size_t)g * 128 * 128 * 25)
                         : (g == 6) ? (Wh + (size_t)384 * 128 * 25)
                                    : (Wm + (size_t)(g - 3) * 128 * 128 * 25);
        packT(hm0, paT0 + (size_t)g * 100 * 4096, 128, 25, 0, 0, 4, 25, 0);
        for (int l = 1; l < 4; ++l) {
            packT(Wx + (size_t)(l - 1) * 896 * 128 * 25,
                  paT[l] + (size_t)g * 200 * 4096, 128, 25, g * 128, 0, 4, 25, 0);
            const float* hmsrc = (g < 3) ? (Wh + ((size_t)l * 512 + g * 128) * 128 * 25)
                               : (g == 6) ? (Wh + ((size_t)l * 512 + 384) * 128 * 25)
                                          : (Wm + ((size_t)l * 384 + (g - 3) * 128) * 128 * 25);
            packT(hmsrc, paT[l] + ((size_t)g * 200 + 100) * 4096, 128, 25, 0, 0, 4, 25, 0);
        }
    }
    for (int l = 0; l < 4; ++l) {
        packT(Wo + (size_t)l * 128 * 256 * 25, oT + (size_t)l * 200 * 4096,
              256, 25, 0, 0, 8, 25, 0);
        packT(Wl + (size_t)l * 128 * 256, lT + (size_t)l * 8 * 4096,
              256, 1, 0, 0, 8, 1, 0);
    }

    for (int t = 0; t < TT; ++t) {
        net_kernel<<<512, 256, 0, stream>>>(frames, mask, xgen, net, t);
        for (int l = 0; l < 4; ++l) {
            unsigned short* hl = hbf + (size_t)l * 1048576;
            // ---- phase A: 14 split-K jobs (7 x-seg -> preA, 7 hm-seg -> preB)
            HJobs14 JA{};
            for (int g = 0; g < 7; ++g) {
                const unsigned short* hmsrc = (g < 3 || g == 6) ? hl : mbf;
                if (l == 0) {
                    JA.j[g] = HJob{ pa0x, pa0x + (size_t)g * 128 * 416, preA + g * 128,
                                    896, 0, HSeg{ net, 4, 0, 0, 0, 0, 1 } };
                    JA.j[7 + g] = HJob{ paT0 + (size_t)g * 100 * 4096, nullptr, preB + g * 128,
                                        896, 0, HSeg{ hmsrc, 7, 0, 4, 0, 25, 1 } };
                } else {
                    JA.j[g] = HJob{ paT[l] + (size_t)g * 200 * 4096, nullptr, preA + g * 128,
                                    896, 0, HSeg{ hbf + (size_t)(l - 1) * 1048576, 7, 0, 4, 0, 25, 1 } };
                    JA.j[7 + g] = HJob{ paT[l] + ((size_t)g * 200 + 100) * 4096, nullptr, preB + g * 128,
                                        896, 0, HSeg{ hmsrc, 7, 0, 4, 0, 25, 1 } };
                }
            }
            hconv_kernel<HJobs14><<<dim3(64, 14), 256, 0, stream>>>(JA, zp);

            gates_kernel<<<4096, 256, 0, stream>>>(preA, preB,
                c0 + (size_t)l * 1048576, m32, mbf, mem);

            // ---- phase B: o-conv split by ci-chunk x8 + lconv
            HJobs9 JB{};
            for (int jj = 0; jj < 8; ++jj)
                JB.j[jj] = HJob{ oT + ((size_t)l * 200 + jj * 25) * 4096, nullptr,
                                 opart + (size_t)jj * 1048576, 128, 0,
                                 HSeg{ mem, 8, jj * 32, 1, 0, 25, 1 } };
            JB.j[8] = HJob{ lT + (size_t)l * 8 * 4096, nullptr, lconv, 128, 0,
                            HSeg{ mem, 8, 0, 8, 0, 1, 0 } };
            hconv_kernel<HJobs9><<<dim3(64, 9), 256, 0, stream>>>(JB, zp);

            hout_kernel<<<4096, 256, 0, stream>>>(preA, preB, opart, lconv, hl);
        }
        wout_kernel<<<512, 256, 0, stream>>>(hbf + (size_t)3 * 1048576, Wout, xgen, out, t);
    }
}